// Round 1
// 150.141 us; speedup vs baseline: 1.2330x; 1.2330x over previous
//
#include <hip/hip_runtime.h>
#include <math.h>

#define CHANNEL 8
#define KDIM 16
#define DFULL 128
#define MNBR 32
#define ROUT_IT 3
#define TM1 64
#define NBS 20   // nbT row stride in dwords (16 data + 4 pad; 16B-aligned)
#define SLP 20   // s_pk row stride in dwords (16 data + 4 pad; 16B-aligned)

typedef __attribute__((ext_vector_type(4))) float f32x4;
typedef __attribute__((ext_vector_type(8))) short short8;
typedef __attribute__((ext_vector_type(8))) _Float16 half8;
typedef __attribute__((ext_vector_type(2))) _Float16 half2v;

// f32 pair -> packed f16 dword (v_cvt_pkrtz_f16_f32, 1 instr)
__device__ inline unsigned pk16(float a, float b) {
  auto r = __builtin_amdgcn_cvt_pkrtz(a, b);
  return __builtin_bit_cast(unsigned, r);
}
// packed-f16 dot2 with f32 accumulate: v_dot2_f32_f16 (1 instr, no unpack)
__device__ inline float fdot2(unsigned a, unsigned b, float c) {
  return __builtin_amdgcn_fdot2(__builtin_bit_cast(half2v, a),
                                __builtin_bit_cast(half2v, b), c, false);
}
__device__ inline float h2f_bits(ushort s) {
  union { ushort u; _Float16 h; } v; v.u = s; return (float)v.h;
}
// DPP reduction step: x + dpp_move<C>(x). 0xB1=quad_perm[1,0,3,2] (xor1),
// 0x4E=quad_perm[2,3,0,1] (xor2), 0x141=row_half_mirror (xor4 after lower
// bits reduced), 0x140=row_mirror (xor8 after lower bits reduced).
template <int C>
__device__ inline float dppadd(float x) {
  int m = __builtin_amdgcn_update_dpp(0, __builtin_bit_cast(int, x), C, 0xF, 0xF, true);
  return x + __builtin_bit_cast(float, m);
}
__device__ inline float dppswap1(float x) {  // value from lane^1
  int m = __builtin_amdgcn_update_dpp(0, __builtin_bit_cast(int, x), 0xB1, 0xF, 0xF, true);
  return __builtin_bit_cast(float, m);
}

union H8 { unsigned u[4]; short8 v; };
__device__ inline short8 pack8h(float4 a, float4 b) {  // 8 f32 -> 8 f16 (RTZ)
  H8 r;
  r.u[0] = pk16(a.x, a.y); r.u[1] = pk16(a.z, a.w);
  r.u[2] = pk16(b.x, b.y); r.u[3] = pk16(b.z, b.w);
  return r.v;
}

// ---------------------------------------------------------------------------
// K0: pack W (128x128 f32) into f16 MFMA B-fragment order:
// frag f = kk*8+j, lane l=(L,H): wpk[(f*64+l)*8 + i] = f16(W[j*16+L][kk*32+H*8+i])
// ---------------------------------------------------------------------------
__global__ __launch_bounds__(256) void wpack_kernel(const float* __restrict__ W,
                                                    ushort* __restrict__ wpk) {
  int task = blockIdx.x * 256 + threadIdx.x;  // 2048 = 32 frags x 64 lanes
  if (task >= 2048) return;
  int f = task >> 6, l = task & 63;
  int kk = f >> 3, j = f & 7, L = l & 15, H = l >> 4;
  const float* src = W + (size_t)(j * 16 + L) * 128 + kk * 32 + H * 8;
  float4 a = *(const float4*)src;
  float4 b = *(const float4*)(src + 4);
  *(short8*)(wpk + (size_t)task * 8) = pack8h(a, b);
}

// ---------------------------------------------------------------------------
// K1: z16[r] = f16(normalize_per_capsule(relu(x @ W^T + b))), row n = 0.
// W fragments staged once into LDS (32 KB) and read via ds_read_b128 — no
// per-wave 32KB global re-reads thrashing L1, no vmem-load register hoard.
// The same LDS is reused for the f32 epilogue transpose (live ranges disjoint).
// ---------------------------------------------------------------------------
__global__ __launch_bounds__(256) void fc_mfma_kernel(
    const float* __restrict__ x, const ushort* __restrict__ wpk,
    const float* __restrict__ bias, ushort* __restrict__ z16, int n) {
  __shared__ __align__(16) float smem[TM1 * 132];  // 33792 B >= 32768 B wpk stage

  const int t = threadIdx.x, lane = t & 63, w = t >> 6;

  // stage wpk (2048 x uint4) -> LDS, coalesced
  {
    const uint4* gw = (const uint4*)wpk;
    uint4* lw = (uint4*)smem;
#pragma unroll
    for (int i = 0; i < 8; ++i) lw[i * 256 + t] = gw[i * 256 + t];
  }

  const int L = lane & 15, H = lane >> 4;
  const int r0 = blockIdx.x * TM1;
  const int row = r0 + w * 16 + L;
  const bool ok = row < n;
  const float4 z4 = make_float4(0.f, 0.f, 0.f, 0.f);

  // A fragments for this wave's 16-row tile, kk = 0..3 (f32 -> f16 in regs)
  const float* xr = x + (size_t)row * DFULL + H * 8;
  short8 af[4];
#pragma unroll
  for (int kk = 0; kk < 4; ++kk) {
    float4 xa = ok ? *(const float4*)(xr + kk * 32) : z4;
    float4 xb = ok ? *(const float4*)(xr + kk * 32 + 4) : z4;
    af[kk] = pack8h(xa, xb);
  }

  f32x4 acc[8];
#pragma unroll
  for (int j = 0; j < 8; ++j) {
    float bv = bias[j * 16 + L];
    acc[j] = (f32x4){bv, bv, bv, bv};
  }
  __syncthreads();  // wpk staged
  const short8* wf = (const short8*)smem;
#pragma unroll
  for (int j = 0; j < 8; ++j)
#pragma unroll
    for (int kk = 0; kk < 4; ++kk) {
      short8 bfr = wf[(kk * 8 + j) * 64 + lane];
      acc[j] = __builtin_amdgcn_mfma_f32_16x16x32_f16(
          __builtin_bit_cast(half8, af[kk]), __builtin_bit_cast(half8, bfr),
          acc[j], 0, 0, 0);
    }
  __syncthreads();  // all waves done reading wpk LDS; reuse as ys

  float* ys = smem;
  const int lr = w * 16 + H * 4;
#pragma unroll
  for (int j = 0; j < 8; ++j)
#pragma unroll
    for (int r = 0; r < 4; ++r)
      ys[(lr + r) * 132 + j * 16 + L] = fmaxf(acc[j][r], 0.f);
  __syncthreads();

  // norm + f16 store: 512 (row,capsule) tasks, 2 per thread
#pragma unroll
  for (int pass = 0; pass < 2; ++pass) {
    int task = t + pass * 256;
    int rr = task >> 3, cc = task & 7;
    const float4* yr = (const float4*)(ys + rr * 132 + cc * 16);
    float4 a = yr[0], b = yr[1], c4 = yr[2], d4 = yr[3];
    float ss = a.x * a.x;
    ss = fmaf(a.y, a.y, ss); ss = fmaf(a.z, a.z, ss); ss = fmaf(a.w, a.w, ss);
    ss = fmaf(b.x, b.x, ss); ss = fmaf(b.y, b.y, ss); ss = fmaf(b.z, b.z, ss);
    ss = fmaf(b.w, b.w, ss); ss = fmaf(c4.x, c4.x, ss); ss = fmaf(c4.y, c4.y, ss);
    ss = fmaf(c4.z, c4.z, ss); ss = fmaf(c4.w, c4.w, ss); ss = fmaf(d4.x, d4.x, ss);
    ss = fmaf(d4.y, d4.y, ss); ss = fmaf(d4.z, d4.z, ss); ss = fmaf(d4.w, d4.w, ss);
    float sc = 1.f / fmaxf(sqrtf(ss), 1e-12f);
    int grow = r0 + rr;
    if (grow < n) {
      uint4 o0, o1;
      o0.x = pk16(a.x * sc, a.y * sc);  o0.y = pk16(a.z * sc, a.w * sc);
      o0.z = pk16(b.x * sc, b.y * sc);  o0.w = pk16(b.z * sc, b.w * sc);
      o1.x = pk16(c4.x * sc, c4.y * sc); o1.y = pk16(c4.z * sc, c4.w * sc);
      o1.z = pk16(d4.x * sc, d4.y * sc); o1.w = pk16(d4.z * sc, d4.w * sc);
      uint4* dst = (uint4*)(z16 + (size_t)grow * DFULL + cc * 16);
      dst[0] = o0; dst[1] = o1;
    } else if (grow == n) {  // pad row = zeros
      uint4 zz = {0u, 0u, 0u, 0u};
      uint4* dst = (uint4*)(z16 + (size_t)grow * DFULL + cc * 16);
      dst[0] = zz; dst[1] = zz;
    }
  }
}

// ---------------------------------------------------------------------------
// K2: routing. 2 nodes/block, node = 2 waves (h = t>>7, g = t&127).
// All pair-FMA work is v_dot2_f32_f16 on packed-f16 dwords (no unpack ops).
// nbT (m-pair-packed columns) read into regs ONCE (iteration-invariant).
// s and u live in LDS packed as f16 pairs; shfl reductions replaced by DPP.
// ---------------------------------------------------------------------------
__global__ __launch_bounds__(256) void routing_kernel(
    const ushort* __restrict__ z16, const int* __restrict__ nid,
    float* __restrict__ out, int n) {
  __shared__ __align__(16) unsigned nbT[2][DFULL * NBS];    // 2 x 10240 B
  __shared__ __align__(16) unsigned slpk[2][CHANNEL * SLP]; // 2 x  640 B
  __shared__ __align__(16) unsigned ulpk[2][64];            // 2 x  256 B

  const int t = threadIdx.x;
  const int h = t >> 7, g = t & 127;
  const int node = 2 * blockIdx.x + h;
  const int p = g >> 3, c = g & 7;       // staging / p-phase role
  const int d = g, uc = g >> 4;          // u-phase role

  // ---- stage: load neighbor rows 2p, 2p+1, channel c (16 f16 each)
  int2 rp = *(const int2*)(nid + node * MNBR + 2 * p);
  const uint4* s0 = (const uint4*)(z16 + (size_t)rp.x * DFULL + c * KDIM);
  const uint4* s1 = (const uint4*)(z16 + (size_t)rp.y * DFULL + c * KDIM);
  uint4 Ra = s0[0], Rb = s0[1];
  uint4 Sa = s1[0], Sb = s1[1];

  unsigned aw[8] = {Ra.x, Ra.y, Ra.z, Ra.w, Rb.x, Rb.y, Rb.z, Rb.w};
  unsigned bw[8] = {Sa.x, Sa.y, Sa.z, Sa.w, Sb.x, Sb.y, Sb.z, Sb.w};
  // transpose-pack into nbT: dword for k holds (row2p[k] lo16, row2p+1[k] hi16)
  {
    unsigned* nb = nbT[h];
    const int pc = (p + 4 * c) & 15;  // bank swizzle, keeps b128 alignment
#pragma unroll
    for (int i = 0; i < 8; ++i) {
      unsigned ev = __builtin_amdgcn_perm(bw[i], aw[i], 0x05040100u);  // k=2i
      unsigned od = __builtin_amdgcn_perm(bw[i], aw[i], 0x07060302u);  // k=2i+1
      nb[(c * KDIM + 2 * i) * NBS + pc] = ev;
      nb[(c * KDIM + 2 * i + 1) * NBS + pc] = od;
    }
  }
  // own row: xk scalar + packed u (iter 0 == z16 row, already f16 pairs)
  unsigned xdw = *((const unsigned*)(z16 + (size_t)node * DFULL) + (d >> 1));
  const float xk = (d & 1) ? h2f_bits((ushort)(xdw >> 16))
                           : h2f_bits((ushort)(xdw & 0xffffu));
  if (!(d & 1)) ulpk[h][d >> 1] = xdw;
  __syncthreads();

  // hoist this thread's nbT column (iteration-invariant) into registers
  const unsigned* nr = nbT[h] + d * NBS;
  const uint4 n0 = *(const uint4*)(nr + 0);
  const uint4 n1 = *(const uint4*)(nr + 4);
  const uint4 n2 = *(const uint4*)(nr + 8);
  const uint4 n3 = *(const uint4*)(nr + 12);
  // iteration-invariant un-swizzled s pointers (pair-group rotation by uc)
  const uint4* sq0 = (const uint4*)(slpk[h] + uc * SLP + 4 * ((0 - uc) & 3));
  const uint4* sq1 = (const uint4*)(slpk[h] + uc * SLP + 4 * ((1 - uc) & 3));
  const uint4* sq2 = (const uint4*)(slpk[h] + uc * SLP + 4 * ((2 - uc) & 3));
  const uint4* sq3 = (const uint4*)(slpk[h] + uc * SLP + 4 * ((3 - uc) & 3));
  const uint4* up = (const uint4*)(ulpk[h] + c * 8);

  for (int it = 0; it < ROUT_IT; ++it) {
    // ---- p-phase: p[m][c] = <u_c, nb_mc> via dot2; softmax over 8 c-lanes
    {
      uint4 u0 = up[0], u1 = up[1];
      float A0 = 0.f, A1 = 0.f;
      A0 = fdot2(aw[0], u0.x, A0); A1 = fdot2(bw[0], u0.x, A1);
      A0 = fdot2(aw[1], u0.y, A0); A1 = fdot2(bw[1], u0.y, A1);
      A0 = fdot2(aw[2], u0.z, A0); A1 = fdot2(bw[2], u0.z, A1);
      A0 = fdot2(aw[3], u0.w, A0); A1 = fdot2(bw[3], u0.w, A1);
      A0 = fdot2(aw[4], u1.x, A0); A1 = fdot2(bw[4], u1.x, A1);
      A0 = fdot2(aw[5], u1.y, A0); A1 = fdot2(bw[5], u1.y, A1);
      A0 = fdot2(aw[6], u1.z, A0); A1 = fdot2(bw[6], u1.z, A1);
      A0 = fdot2(aw[7], u1.w, A0); A1 = fdot2(bw[7], u1.w, A1);
      float e0 = __expf(A0), e1 = __expf(A1);  // |p| <= 1, no max-sub needed
      // softmax denom across the 8 c-lanes (contiguous, 8-aligned) via DPP
      float d0 = dppadd<0xB1>(e0);  float d1 = dppadd<0xB1>(e1);
      d0 = dppadd<0x4E>(d0);        d1 = dppadd<0x4E>(d1);
      d0 = dppadd<0x141>(d0);       d1 = dppadd<0x141>(d1);
      float ir0 = __builtin_amdgcn_rcpf(d0);
      float ir1 = __builtin_amdgcn_rcpf(d1);
      slpk[h][c * SLP + p] = pk16(e0 * ir0, e1 * ir1);  // (s[2p], s[2p+1]) f16
    }
    __syncthreads();
    // ---- u-phase: u[d] = xk + sum_m s[m][c]*nb[m][d], all via dot2
    {
      uint4 v0 = *sq0, v1 = *sq1, v2 = *sq2, v3 = *sq3;
      float A0 = xk, A1 = 0.f;
      A0 = fdot2(n0.x, v0.x, A0); A1 = fdot2(n2.x, v2.x, A1);
      A0 = fdot2(n0.y, v0.y, A0); A1 = fdot2(n2.y, v2.y, A1);
      A0 = fdot2(n0.z, v0.z, A0); A1 = fdot2(n2.z, v2.z, A1);
      A0 = fdot2(n0.w, v0.w, A0); A1 = fdot2(n2.w, v2.w, A1);
      A0 = fdot2(n1.x, v1.x, A0); A1 = fdot2(n3.x, v3.x, A1);
      A0 = fdot2(n1.y, v1.y, A0); A1 = fdot2(n3.y, v3.y, A1);
      A0 = fdot2(n1.z, v1.z, A0); A1 = fdot2(n3.z, v3.z, A1);
      A0 = fdot2(n1.w, v1.w, A0); A1 = fdot2(n3.w, v3.w, A1);
      float u = A0 + A1;
      if (it == ROUT_IT - 1) {
        out[(size_t)node * DFULL + d] = u;
      } else {
        // capsule norm over the 16 k-lanes (contiguous, 16-aligned) via DPP
        float ssq = u * u;
        ssq = dppadd<0xB1>(ssq);
        ssq = dppadd<0x4E>(ssq);
        ssq = dppadd<0x141>(ssq);
        ssq = dppadd<0x140>(ssq);
        float sc = 1.f / fmaxf(sqrtf(ssq), 1e-12f);
        float un = u * sc;
        float uo = dppswap1(un);  // neighbor k-lane's value
        if (!(d & 1)) ulpk[h][d >> 1] = pk16(un, uo);  // (u[2i], u[2i+1]) f16
      }
    }
    __syncthreads();
  }
}

// ---------------------------------------------------------------------------
extern "C" void kernel_launch(void* const* d_in, const int* in_sizes, int n_in,
                              void* d_out, int out_size, void* d_ws, size_t ws_size,
                              hipStream_t stream) {
  const float* x = (const float*)d_in[0];
  const float* W = (const float*)d_in[1];
  const float* b = (const float*)d_in[2];
  const int* nid = (const int*)d_in[3];
  float* out = (float*)d_out;

  int n = in_sizes[0] / DFULL;            // 50000
  int g1 = (n + 1 + TM1 - 1) / TM1;       // 782 (covers rows 0..n)
  size_t zrows = (size_t)g1 * TM1;        // 50048

  ushort* z16 = (ushort*)d_ws;                   // zrows x 128 f16 table
  ushort* wpk = (ushort*)d_ws + zrows * DFULL;   // 2048 x 8 f16 W fragments

  wpack_kernel<<<8, 256, 0, stream>>>(W, wpk);
  fc_mfma_kernel<<<g1, 256, 0, stream>>>(x, wpk, b, z16, n);
  routing_kernel<<<n / 2, 256, 0, stream>>>(z16, nid, out, n);
}

// Round 2
// 149.567 us; speedup vs baseline: 1.2377x; 1.0038x over previous
//
#include <hip/hip_runtime.h>
#include <math.h>

#define CHANNEL 8
#define KDIM 16
#define DFULL 128
#define MNBR 32
#define ROUT_IT 3
#define TM1 64
#define NBS 20   // nbT/slT row stride in dwords (16 data + 4 pad; 16B-aligned)

typedef __attribute__((ext_vector_type(4))) float f32x4;
typedef __attribute__((ext_vector_type(8))) short short8;
typedef __attribute__((ext_vector_type(8))) _Float16 half8;
typedef __attribute__((ext_vector_type(2))) _Float16 half2v;

// f32 pair -> packed f16 dword (v_cvt_pkrtz_f16_f32, 1 instr)
__device__ inline unsigned pk16(float a, float b) {
  auto r = __builtin_amdgcn_cvt_pkrtz(a, b);
  return __builtin_bit_cast(unsigned, r);
}
// packed-f16 dot2 with f32 accumulate: v_dot2_f32_f16 (1 instr, no unpack)
__device__ inline float fdot2(unsigned a, unsigned b, float c) {
  return __builtin_amdgcn_fdot2(__builtin_bit_cast(half2v, a),
                                __builtin_bit_cast(half2v, b), c, false);
}
__device__ inline float h2f_lo(unsigned w) {
  union { ushort u; _Float16 h; } v; v.u = (ushort)(w & 0xffffu); return (float)v.h;
}
__device__ inline float h2f_hi(unsigned w) {
  union { ushort u; _Float16 h; } v; v.u = (ushort)(w >> 16); return (float)v.h;
}
// DPP reduction step: x + dpp_move<C>(x). 0xB1=quad_perm[1,0,3,2] (xor1),
// 0x4E=quad_perm[2,3,0,1] (xor2), 0x141=row_half_mirror (xor4 once lower bits
// uniform), 0x140=row_mirror (xor8 once lower bits uniform).
template <int C>
__device__ inline float dppadd(float x) {
  int m = __builtin_amdgcn_update_dpp(0, __builtin_bit_cast(int, x), C, 0xF, 0xF, true);
  return x + __builtin_bit_cast(float, m);
}
__device__ inline float dppswap1(float x) {  // value from lane^1
  int m = __builtin_amdgcn_update_dpp(0, __builtin_bit_cast(int, x), 0xB1, 0xF, 0xF, true);
  return __builtin_bit_cast(float, m);
}

union H8 { unsigned u[4]; short8 v; };
__device__ inline short8 pack8h(float4 a, float4 b) {  // 8 f32 -> 8 f16 (RTZ)
  H8 r;
  r.u[0] = pk16(a.x, a.y); r.u[1] = pk16(a.z, a.w);
  r.u[2] = pk16(b.x, b.y); r.u[3] = pk16(b.z, b.w);
  return r.v;
}

// ---------------------------------------------------------------------------
// K0: pack W (128x128 f32) into f16 MFMA B-fragment order.
// ---------------------------------------------------------------------------
__global__ __launch_bounds__(256) void wpack_kernel(const float* __restrict__ W,
                                                    ushort* __restrict__ wpk) {
  int task = blockIdx.x * 256 + threadIdx.x;  // 2048 = 32 frags x 64 lanes
  if (task >= 2048) return;
  int f = task >> 6, l = task & 63;
  int kk = f >> 3, j = f & 7, L = l & 15, H = l >> 4;
  const float* src = W + (size_t)(j * 16 + L) * 128 + kk * 32 + H * 8;
  float4 a = *(const float4*)src;
  float4 b = *(const float4*)(src + 4);
  *(short8*)(wpk + (size_t)task * 8) = pack8h(a, b);
}

// ---------------------------------------------------------------------------
// K1: z16[r] = f16(normalize_per_capsule(relu(x @ W^T + b))), row n = 0.
// (unchanged from round 1)
// ---------------------------------------------------------------------------
__global__ __launch_bounds__(256) void fc_mfma_kernel(
    const float* __restrict__ x, const ushort* __restrict__ wpk,
    const float* __restrict__ bias, ushort* __restrict__ z16, int n) {
  __shared__ __align__(16) float smem[TM1 * 132];  // 33792 B >= 32768 B wpk stage

  const int t = threadIdx.x, lane = t & 63, w = t >> 6;

  {
    const uint4* gw = (const uint4*)wpk;
    uint4* lw = (uint4*)smem;
#pragma unroll
    for (int i = 0; i < 8; ++i) lw[i * 256 + t] = gw[i * 256 + t];
  }

  const int L = lane & 15, H = lane >> 4;
  const int r0 = blockIdx.x * TM1;
  const int row = r0 + w * 16 + L;
  const bool ok = row < n;
  const float4 z4 = make_float4(0.f, 0.f, 0.f, 0.f);

  const float* xr = x + (size_t)row * DFULL + H * 8;
  short8 af[4];
#pragma unroll
  for (int kk = 0; kk < 4; ++kk) {
    float4 xa = ok ? *(const float4*)(xr + kk * 32) : z4;
    float4 xb = ok ? *(const float4*)(xr + kk * 32 + 4) : z4;
    af[kk] = pack8h(xa, xb);
  }

  f32x4 acc[8];
#pragma unroll
  for (int j = 0; j < 8; ++j) {
    float bv = bias[j * 16 + L];
    acc[j] = (f32x4){bv, bv, bv, bv};
  }
  __syncthreads();  // wpk staged
  const short8* wf = (const short8*)smem;
#pragma unroll
  for (int j = 0; j < 8; ++j)
#pragma unroll
    for (int kk = 0; kk < 4; ++kk) {
      short8 bfr = wf[(kk * 8 + j) * 64 + lane];
      acc[j] = __builtin_amdgcn_mfma_f32_16x16x32_f16(
          __builtin_bit_cast(half8, af[kk]), __builtin_bit_cast(half8, bfr),
          acc[j], 0, 0, 0);
    }
  __syncthreads();  // all waves done reading wpk LDS; reuse as ys

  float* ys = smem;
  const int lr = w * 16 + H * 4;
#pragma unroll
  for (int j = 0; j < 8; ++j)
#pragma unroll
    for (int r = 0; r < 4; ++r)
      ys[(lr + r) * 132 + j * 16 + L] = fmaxf(acc[j][r], 0.f);
  __syncthreads();

#pragma unroll
  for (int pass = 0; pass < 2; ++pass) {
    int task = t + pass * 256;
    int rr = task >> 3, cc = task & 7;
    const float4* yr = (const float4*)(ys + rr * 132 + cc * 16);
    float4 a = yr[0], b = yr[1], c4 = yr[2], d4 = yr[3];
    float ss = a.x * a.x;
    ss = fmaf(a.y, a.y, ss); ss = fmaf(a.z, a.z, ss); ss = fmaf(a.w, a.w, ss);
    ss = fmaf(b.x, b.x, ss); ss = fmaf(b.y, b.y, ss); ss = fmaf(b.z, b.z, ss);
    ss = fmaf(b.w, b.w, ss); ss = fmaf(c4.x, c4.x, ss); ss = fmaf(c4.y, c4.y, ss);
    ss = fmaf(c4.z, c4.z, ss); ss = fmaf(c4.w, c4.w, ss); ss = fmaf(d4.x, d4.x, ss);
    ss = fmaf(d4.y, d4.y, ss); ss = fmaf(d4.z, d4.z, ss); ss = fmaf(d4.w, d4.w, ss);
    float sc = 1.f / fmaxf(sqrtf(ss), 1e-12f);
    int grow = r0 + rr;
    if (grow < n) {
      uint4 o0, o1;
      o0.x = pk16(a.x * sc, a.y * sc);  o0.y = pk16(a.z * sc, a.w * sc);
      o0.z = pk16(b.x * sc, b.y * sc);  o0.w = pk16(b.z * sc, b.w * sc);
      o1.x = pk16(c4.x * sc, c4.y * sc); o1.y = pk16(c4.z * sc, c4.w * sc);
      o1.z = pk16(d4.x * sc, d4.y * sc); o1.w = pk16(d4.z * sc, d4.w * sc);
      uint4* dst = (uint4*)(z16 + (size_t)grow * DFULL + cc * 16);
      dst[0] = o0; dst[1] = o1;
    } else if (grow == n) {  // pad row = zeros
      uint4 zz = {0u, 0u, 0u, 0u};
      uint4* dst = (uint4*)(z16 + (size_t)grow * DFULL + cc * 16);
      dst[0] = zz; dst[1] = zz;
    }
  }
}

// ---------------------------------------------------------------------------
// K2: routing, ONE WAVE PER NODE, barrier-free.
// Intra-wave LDS producer->consumer relies on the per-wave in-order DS pipe;
// asm lgkmcnt(0)+memory-clobber fences only stop compiler reordering.
// p-phase: lane (q=lane>>3, c=lane&7) owns neighbor rows 4q..4q+3, channel c
//          in regs; softmax denom via 3-level DPP over the 8 c-lanes.
// u-phase: lane owns d=lane and d=lane+64; nbT columns (m-pair-packed f16,
//          stride 20, slot swizzle (mp+4c)&15) hoisted to regs ONCE; s read
//          as rotated b128; capsule norm via 4-level DPP over 16 k-lanes.
// ---------------------------------------------------------------------------
__global__ __launch_bounds__(128, 3) void routing_kernel(
    const ushort* __restrict__ z16, const int* __restrict__ nid,
    float* __restrict__ out, int n) {
  __shared__ __align__(16) unsigned nbT[2][DFULL * NBS];    // 2 x 10240 B
  __shared__ __align__(16) unsigned slT[2][CHANNEL * NBS];  // 2 x   640 B
  __shared__ __align__(16) unsigned ulk[2][64];             // 2 x   256 B

  const int t = threadIdx.x;
  const int wv = t >> 6, lane = t & 63;
  const int node = blockIdx.x * 2 + wv;
  const int q = lane >> 3, c = lane & 7;  // p-phase / staging role
  const int cu = lane >> 4;               // capsule of d = lane (and +4 for d+64)

  // ---- stage: this lane loads neighbor rows 4q..4q+3, channel c (16 f16 each)
  int4 ids = *(const int4*)(nid + node * MNBR + 4 * q);
  const uint4* g0 = (const uint4*)(z16 + (size_t)ids.x * DFULL + c * KDIM);
  const uint4* g1 = (const uint4*)(z16 + (size_t)ids.y * DFULL + c * KDIM);
  const uint4* g2 = (const uint4*)(z16 + (size_t)ids.z * DFULL + c * KDIM);
  const uint4* g3 = (const uint4*)(z16 + (size_t)ids.w * DFULL + c * KDIM);
  uint4 R0a = g0[0], R0b = g0[1];
  uint4 R1a = g1[0], R1b = g1[1];
  uint4 R2a = g2[0], R2b = g2[1];
  uint4 R3a = g3[0], R3b = g3[1];

  // own row: seed packed u (iter 0 = z16 row, already f16 pairs) + xk scalars
  const unsigned* zdw = (const unsigned*)z16;
  ulk[wv][lane] = zdw[(size_t)node * 64 + lane];
  unsigned xw0 = zdw[(size_t)node * 64 + (lane >> 1)];
  unsigned xw1 = zdw[(size_t)node * 64 + 32 + (lane >> 1)];
  const float xk0 = (lane & 1) ? h2f_hi(xw0) : h2f_lo(xw0);
  const float xk1 = (lane & 1) ? h2f_hi(xw1) : h2f_lo(xw1);

  unsigned r0[8] = {R0a.x, R0a.y, R0a.z, R0a.w, R0b.x, R0b.y, R0b.z, R0b.w};
  unsigned r1[8] = {R1a.x, R1a.y, R1a.z, R1a.w, R1b.x, R1b.y, R1b.z, R1b.w};
  unsigned r2[8] = {R2a.x, R2a.y, R2a.z, R2a.w, R2b.x, R2b.y, R2b.z, R2b.w};
  unsigned r3[8] = {R3a.x, R3a.y, R3a.z, R3a.w, R3b.x, R3b.y, R3b.z, R3b.w};

  // transpose-pack into nbT: dword (d, m-pair mp) = (row_even[k] lo, row_odd[k] hi)
  {
    unsigned* nb = nbT[wv];
    const int sl0 = (2 * q + 4 * c) & 15;      // slot swizzle (b128-group safe)
    const int sl1 = (2 * q + 1 + 4 * c) & 15;
#pragma unroll
    for (int i = 0; i < 8; ++i) {
      unsigned ev0 = __builtin_amdgcn_perm(r1[i], r0[i], 0x05040100u);  // k=2i
      unsigned od0 = __builtin_amdgcn_perm(r1[i], r0[i], 0x07060302u);  // k=2i+1
      unsigned ev1 = __builtin_amdgcn_perm(r3[i], r2[i], 0x05040100u);
      unsigned od1 = __builtin_amdgcn_perm(r3[i], r2[i], 0x07060302u);
      nb[(c * KDIM + 2 * i) * NBS + sl0] = ev0;
      nb[(c * KDIM + 2 * i + 1) * NBS + sl0] = od0;
      nb[(c * KDIM + 2 * i) * NBS + sl1] = ev1;
      nb[(c * KDIM + 2 * i + 1) * NBS + sl1] = od1;
    }
  }
  asm volatile("s_waitcnt lgkmcnt(0)" ::: "memory");  // intra-wave fence

  // hoist this lane's two nbT columns (iteration-invariant) into registers
  const unsigned* colA = nbT[wv] + lane * NBS;
  const unsigned* colB = nbT[wv] + (lane + 64) * NBS;
  const uint4 nA0 = *(const uint4*)(colA + 0);
  const uint4 nA1 = *(const uint4*)(colA + 4);
  const uint4 nA2 = *(const uint4*)(colA + 8);
  const uint4 nA3 = *(const uint4*)(colA + 12);
  const uint4 nB0 = *(const uint4*)(colB + 0);
  const uint4 nB1 = *(const uint4*)(colB + 4);
  const uint4 nB2 = *(const uint4*)(colB + 8);
  const uint4 nB3 = *(const uint4*)(colB + 12);

  // iteration-invariant pointers
  const uint4* upk = (const uint4*)(ulk[wv] + c * 8);
  const int o0 = 4 * ((0 - cu) & 3), o1 = 4 * ((1 - cu) & 3),
            o2 = 4 * ((2 - cu) & 3), o3 = 4 * ((3 - cu) & 3);
  const unsigned* sA = slT[wv] + cu * NBS;
  const unsigned* sB = slT[wv] + (cu + 4) * NBS;
  uint2* swr = (uint2*)(slT[wv]) + c * (NBS / 2) + q;

#pragma unroll
  for (int it = 0; it < ROUT_IT; ++it) {
    // ---- p-phase: 4 agreement dots from regs; softmax over 8 c-lanes
    {
      uint4 ua = upk[0], ub = upk[1];
      float A0 = 0.f, A1 = 0.f, A2 = 0.f, A3 = 0.f;
      A0 = fdot2(r0[0], ua.x, A0); A1 = fdot2(r1[0], ua.x, A1);
      A2 = fdot2(r2[0], ua.x, A2); A3 = fdot2(r3[0], ua.x, A3);
      A0 = fdot2(r0[1], ua.y, A0); A1 = fdot2(r1[1], ua.y, A1);
      A2 = fdot2(r2[1], ua.y, A2); A3 = fdot2(r3[1], ua.y, A3);
      A0 = fdot2(r0[2], ua.z, A0); A1 = fdot2(r1[2], ua.z, A1);
      A2 = fdot2(r2[2], ua.z, A2); A3 = fdot2(r3[2], ua.z, A3);
      A0 = fdot2(r0[3], ua.w, A0); A1 = fdot2(r1[3], ua.w, A1);
      A2 = fdot2(r2[3], ua.w, A2); A3 = fdot2(r3[3], ua.w, A3);
      A0 = fdot2(r0[4], ub.x, A0); A1 = fdot2(r1[4], ub.x, A1);
      A2 = fdot2(r2[4], ub.x, A2); A3 = fdot2(r3[4], ub.x, A3);
      A0 = fdot2(r0[5], ub.y, A0); A1 = fdot2(r1[5], ub.y, A1);
      A2 = fdot2(r2[5], ub.y, A2); A3 = fdot2(r3[5], ub.y, A3);
      A0 = fdot2(r0[6], ub.z, A0); A1 = fdot2(r1[6], ub.z, A1);
      A2 = fdot2(r2[6], ub.z, A2); A3 = fdot2(r3[6], ub.z, A3);
      A0 = fdot2(r0[7], ub.w, A0); A1 = fdot2(r1[7], ub.w, A1);
      A2 = fdot2(r2[7], ub.w, A2); A3 = fdot2(r3[7], ub.w, A3);
      float e0 = __expf(A0), e1 = __expf(A1), e2 = __expf(A2), e3 = __expf(A3);
      float D0 = dppadd<0x141>(dppadd<0x4E>(dppadd<0xB1>(e0)));
      float D1 = dppadd<0x141>(dppadd<0x4E>(dppadd<0xB1>(e1)));
      float D2 = dppadd<0x141>(dppadd<0x4E>(dppadd<0xB1>(e2)));
      float D3 = dppadd<0x141>(dppadd<0x4E>(dppadd<0xB1>(e3)));
      float s0 = e0 * __builtin_amdgcn_rcpf(D0);
      float s1 = e1 * __builtin_amdgcn_rcpf(D1);
      float s2 = e2 * __builtin_amdgcn_rcpf(D2);
      float s3 = e3 * __builtin_amdgcn_rcpf(D3);
      uint2 sw; sw.x = pk16(s0, s1); sw.y = pk16(s2, s3);
      *swr = sw;  // slots 2q, 2q+1 of row c
    }
    asm volatile("s_waitcnt lgkmcnt(0)" ::: "memory");  // s visible to wave
    // ---- u-phase: u[d] = xk + sum_m s[m][c]*nb[m][d] for d=lane, lane+64
    {
      uint4 v;
      float a = xk0, b = 0.f;
      v = *(const uint4*)(sA + o0);
      a = fdot2(nA0.x, v.x, a); b = fdot2(nA0.y, v.y, b);
      a = fdot2(nA0.z, v.z, a); b = fdot2(nA0.w, v.w, b);
      v = *(const uint4*)(sA + o1);
      a = fdot2(nA1.x, v.x, a); b = fdot2(nA1.y, v.y, b);
      a = fdot2(nA1.z, v.z, a); b = fdot2(nA1.w, v.w, b);
      v = *(const uint4*)(sA + o2);
      a = fdot2(nA2.x, v.x, a); b = fdot2(nA2.y, v.y, b);
      a = fdot2(nA2.z, v.z, a); b = fdot2(nA2.w, v.w, b);
      v = *(const uint4*)(sA + o3);
      a = fdot2(nA3.x, v.x, a); b = fdot2(nA3.y, v.y, b);
      a = fdot2(nA3.z, v.z, a); b = fdot2(nA3.w, v.w, b);
      float u0 = a + b;
      float e = xk1, f = 0.f;
      v = *(const uint4*)(sB + o0);
      e = fdot2(nB0.x, v.x, e); f = fdot2(nB0.y, v.y, f);
      e = fdot2(nB0.z, v.z, e); f = fdot2(nB0.w, v.w, f);
      v = *(const uint4*)(sB + o1);
      e = fdot2(nB1.x, v.x, e); f = fdot2(nB1.y, v.y, f);
      e = fdot2(nB1.z, v.z, e); f = fdot2(nB1.w, v.w, f);
      v = *(const uint4*)(sB + o2);
      e = fdot2(nB2.x, v.x, e); f = fdot2(nB2.y, v.y, f);
      e = fdot2(nB2.z, v.z, e); f = fdot2(nB2.w, v.w, f);
      v = *(const uint4*)(sB + o3);
      e = fdot2(nB3.x, v.x, e); f = fdot2(nB3.y, v.y, f);
      e = fdot2(nB3.z, v.z, e); f = fdot2(nB3.w, v.w, f);
      float u1 = e + f;
      if (it == ROUT_IT - 1) {
        out[(size_t)node * DFULL + lane] = u0;
        out[(size_t)node * DFULL + 64 + lane] = u1;
      } else {
        float ss0 = u0 * u0;  // capsule norm over 16 k-lanes
        ss0 = dppadd<0xB1>(ss0); ss0 = dppadd<0x4E>(ss0);
        ss0 = dppadd<0x141>(ss0); ss0 = dppadd<0x140>(ss0);
        float ss1 = u1 * u1;
        ss1 = dppadd<0xB1>(ss1); ss1 = dppadd<0x4E>(ss1);
        ss1 = dppadd<0x141>(ss1); ss1 = dppadd<0x140>(ss1);
        float sc0 = __builtin_amdgcn_rsqf(fmaxf(ss0, 1e-24f));
        float sc1 = __builtin_amdgcn_rsqf(fmaxf(ss1, 1e-24f));
        float un0 = u0 * sc0, un1 = u1 * sc1;
        float p0 = dppswap1(un0), p1 = dppswap1(un1);
        if (!(lane & 1)) {
          ulk[wv][lane >> 1] = pk16(un0, p0);
          ulk[wv][32 + (lane >> 1)] = pk16(un1, p1);
        }
      }
    }
    asm volatile("s_waitcnt lgkmcnt(0)" ::: "memory");  // u visible to wave
  }
}

// ---------------------------------------------------------------------------
extern "C" void kernel_launch(void* const* d_in, const int* in_sizes, int n_in,
                              void* d_out, int out_size, void* d_ws, size_t ws_size,
                              hipStream_t stream) {
  const float* x = (const float*)d_in[0];
  const float* W = (const float*)d_in[1];
  const float* b = (const float*)d_in[2];
  const int* nid = (const int*)d_in[3];
  float* out = (float*)d_out;

  int n = in_sizes[0] / DFULL;            // 50000
  int g1 = (n + 1 + TM1 - 1) / TM1;       // 782 (covers rows 0..n)
  size_t zrows = (size_t)g1 * TM1;        // 50048

  ushort* z16 = (ushort*)d_ws;                   // zrows x 128 f16 table
  ushort* wpk = (ushort*)d_ws + zrows * DFULL;   // 2048 x 8 f16 W fragments

  wpack_kernel<<<8, 256, 0, stream>>>(W, wpk);
  fc_mfma_kernel<<<g1, 256, 0, stream>>>(x, wpk, b, z16, n);
  routing_kernel<<<n / 2, 128, 0, stream>>>(z16, nid, out, n);
}

// Round 3
// 143.891 us; speedup vs baseline: 1.2865x; 1.0395x over previous
//
#include <hip/hip_runtime.h>
#include <math.h>

#define CHANNEL 8
#define KDIM 16
#define DFULL 128
#define MNBR 32
#define ROUT_IT 3
#define TM1 64

typedef __attribute__((ext_vector_type(4))) float f32x4;
typedef __attribute__((ext_vector_type(8))) short short8;
typedef __attribute__((ext_vector_type(8))) _Float16 half8;
typedef __attribute__((ext_vector_type(2))) _Float16 half2v;

// f32 pair -> packed f16 dword (v_cvt_pkrtz_f16_f32, 1 instr)
__device__ inline unsigned pk16(float a, float b) {
  auto r = __builtin_amdgcn_cvt_pkrtz(a, b);
  return __builtin_bit_cast(unsigned, r);
}
// packed-f16 dot2 with f32 accumulate: v_dot2_f32_f16 (1 instr, no unpack)
__device__ inline float fdot2(unsigned a, unsigned b, float c) {
  return __builtin_amdgcn_fdot2(__builtin_bit_cast(half2v, a),
                                __builtin_bit_cast(half2v, b), c, false);
}
__device__ inline float h2f_lo(unsigned w) {
  union { ushort u; _Float16 h; } v; v.u = (ushort)(w & 0xffffu); return (float)v.h;
}
__device__ inline float h2f_hi(unsigned w) {
  union { ushort u; _Float16 h; } v; v.u = (ushort)(w >> 16); return (float)v.h;
}
// packed f16 helpers (v_pk_fma_f16 / v_pk_add_f16 / v_pk_mul_f16)
__device__ inline half2v h2(unsigned u) { return __builtin_bit_cast(half2v, u); }
__device__ inline unsigned unh(half2v h) { return __builtin_bit_cast(unsigned, h); }
__device__ inline unsigned pkfma16(unsigned a, unsigned b, unsigned c) {
  return unh(__builtin_elementwise_fma(h2(a), h2(b), h2(c)));
}
// DPP reduction step: x + dpp_move<C>(x). 0xB1=quad_perm xor1, 0x4E=quad_perm
// xor2, 0x141=row_half_mirror (xor4 once lower 2 bits uniform).
template <int C>
__device__ inline float dppadd(float x) {
  int m = __builtin_amdgcn_update_dpp(0, __builtin_bit_cast(int, x), C, 0xF, 0xF, true);
  return x + __builtin_bit_cast(float, m);
}

union H8 { unsigned u[4]; short8 v; };
__device__ inline short8 pack8h(float4 a, float4 b) {  // 8 f32 -> 8 f16 (RTZ)
  H8 r;
  r.u[0] = pk16(a.x, a.y); r.u[1] = pk16(a.z, a.w);
  r.u[2] = pk16(b.x, b.y); r.u[3] = pk16(b.z, b.w);
  return r.v;
}

// ---------------------------------------------------------------------------
// K0: pack W (128x128 f32) into f16 MFMA B-fragment order. (unchanged)
// ---------------------------------------------------------------------------
__global__ __launch_bounds__(256) void wpack_kernel(const float* __restrict__ W,
                                                    ushort* __restrict__ wpk) {
  int task = blockIdx.x * 256 + threadIdx.x;  // 2048 = 32 frags x 64 lanes
  if (task >= 2048) return;
  int f = task >> 6, l = task & 63;
  int kk = f >> 3, j = f & 7, L = l & 15, H = l >> 4;
  const float* src = W + (size_t)(j * 16 + L) * 128 + kk * 32 + H * 8;
  float4 a = *(const float4*)src;
  float4 b = *(const float4*)(src + 4);
  *(short8*)(wpk + (size_t)task * 8) = pack8h(a, b);
}

// ---------------------------------------------------------------------------
// K1: z16[r] = f16(normalize_per_capsule(relu(x @ W^T + b))), row n = 0.
// (unchanged from round 2 — one variable per round; its counters will show
// in top-5 next round now that routing drops below it)
// ---------------------------------------------------------------------------
__global__ __launch_bounds__(256) void fc_mfma_kernel(
    const float* __restrict__ x, const ushort* __restrict__ wpk,
    const float* __restrict__ bias, ushort* __restrict__ z16, int n) {
  __shared__ __align__(16) float smem[TM1 * 132];  // 33792 B >= 32768 B wpk stage

  const int t = threadIdx.x, lane = t & 63, w = t >> 6;

  {
    const uint4* gw = (const uint4*)wpk;
    uint4* lw = (uint4*)smem;
#pragma unroll
    for (int i = 0; i < 8; ++i) lw[i * 256 + t] = gw[i * 256 + t];
  }

  const int L = lane & 15, H = lane >> 4;
  const int r0 = blockIdx.x * TM1;
  const int row = r0 + w * 16 + L;
  const bool ok = row < n;
  const float4 z4 = make_float4(0.f, 0.f, 0.f, 0.f);

  const float* xr = x + (size_t)row * DFULL + H * 8;
  short8 af[4];
#pragma unroll
  for (int kk = 0; kk < 4; ++kk) {
    float4 xa = ok ? *(const float4*)(xr + kk * 32) : z4;
    float4 xb = ok ? *(const float4*)(xr + kk * 32 + 4) : z4;
    af[kk] = pack8h(xa, xb);
  }

  f32x4 acc[8];
#pragma unroll
  for (int j = 0; j < 8; ++j) {
    float bv = bias[j * 16 + L];
    acc[j] = (f32x4){bv, bv, bv, bv};
  }
  __syncthreads();  // wpk staged
  const short8* wf = (const short8*)smem;
#pragma unroll
  for (int j = 0; j < 8; ++j)
#pragma unroll
    for (int kk = 0; kk < 4; ++kk) {
      short8 bfr = wf[(kk * 8 + j) * 64 + lane];
      acc[j] = __builtin_amdgcn_mfma_f32_16x16x32_f16(
          __builtin_bit_cast(half8, af[kk]), __builtin_bit_cast(half8, bfr),
          acc[j], 0, 0, 0);
    }
  __syncthreads();  // all waves done reading wpk LDS; reuse as ys

  float* ys = smem;
  const int lr = w * 16 + H * 4;
#pragma unroll
  for (int j = 0; j < 8; ++j)
#pragma unroll
    for (int r = 0; r < 4; ++r)
      ys[(lr + r) * 132 + j * 16 + L] = fmaxf(acc[j][r], 0.f);
  __syncthreads();

#pragma unroll
  for (int pass = 0; pass < 2; ++pass) {
    int task = t + pass * 256;
    int rr = task >> 3, cc = task & 7;
    const float4* yr = (const float4*)(ys + rr * 132 + cc * 16);
    float4 a = yr[0], b = yr[1], c4 = yr[2], d4 = yr[3];
    float ss = a.x * a.x;
    ss = fmaf(a.y, a.y, ss); ss = fmaf(a.z, a.z, ss); ss = fmaf(a.w, a.w, ss);
    ss = fmaf(b.x, b.x, ss); ss = fmaf(b.y, b.y, ss); ss = fmaf(b.z, b.z, ss);
    ss = fmaf(b.w, b.w, ss); ss = fmaf(c4.x, c4.x, ss); ss = fmaf(c4.y, c4.y, ss);
    ss = fmaf(c4.z, c4.z, ss); ss = fmaf(c4.w, c4.w, ss); ss = fmaf(d4.x, d4.x, ss);
    ss = fmaf(d4.y, d4.y, ss); ss = fmaf(d4.z, d4.z, ss); ss = fmaf(d4.w, d4.w, ss);
    float sc = 1.f / fmaxf(sqrtf(ss), 1e-12f);
    int grow = r0 + rr;
    if (grow < n) {
      uint4 o0, o1;
      o0.x = pk16(a.x * sc, a.y * sc);  o0.y = pk16(a.z * sc, a.w * sc);
      o0.z = pk16(b.x * sc, b.y * sc);  o0.w = pk16(b.z * sc, b.w * sc);
      o1.x = pk16(c4.x * sc, c4.y * sc); o1.y = pk16(c4.z * sc, c4.w * sc);
      o1.z = pk16(d4.x * sc, d4.y * sc); o1.w = pk16(d4.z * sc, d4.w * sc);
      uint4* dst = (uint4*)(z16 + (size_t)grow * DFULL + cc * 16);
      dst[0] = o0; dst[1] = o1;
    } else if (grow == n) {  // pad row = zeros
      uint4 zz = {0u, 0u, 0u, 0u};
      uint4* dst = (uint4*)(z16 + (size_t)grow * DFULL + cc * 16);
      dst[0] = zz; dst[1] = zz;
    }
  }
}

// ---------------------------------------------------------------------------
// K2: routing — FULLY REGISTER-RESIDENT. Zero LDS arrays, zero barriers.
// One wave per node (4 nodes / 256-thr block). Lane (q=lane>>3, c=lane&7)
// owns neighbor rows 4q..4q+3, channel c (4 x 8 packed-f16 dwords in regs).
// p-phase: 32 fdot2 from regs; softmax over the 8 contiguous c-lanes via DPP.
// u-phase: lane's own s0..s3 weight its own rows (32 v_pk_fma_f16) ->
//   butterfly sum over q-lanes: XOR8/XOR16 = ds_swizzle (conflict-free
//   crossbar), XOR32 = __shfl_xor (ds_bpermute, full 64-lane on gfx9).
// Every lane ends with the complete u[c]; norm is 8 local fdot2 + rsq.
// ---------------------------------------------------------------------------
__global__ __launch_bounds__(256, 4) void routing_kernel(
    const ushort* __restrict__ z16, const int* __restrict__ nid,
    float* __restrict__ out, int n) {
  const int t = threadIdx.x;
  const int node = blockIdx.x * 4 + (t >> 6);
  if (node >= n) return;
  const int lane = t & 63;
  const int q = lane >> 3, c = lane & 7;

  // ---- load this lane's 4 neighbor-row channel slices (16 f16 = 32B each).
  // Lanes c=0..7 of a q-group cover each 256B row contiguously (coalesced).
  int4 ids = *(const int4*)(nid + node * MNBR + 4 * q);
  const uint4* g0 = (const uint4*)(z16 + (size_t)ids.x * DFULL + c * KDIM);
  const uint4* g1 = (const uint4*)(z16 + (size_t)ids.y * DFULL + c * KDIM);
  const uint4* g2 = (const uint4*)(z16 + (size_t)ids.z * DFULL + c * KDIM);
  const uint4* g3 = (const uint4*)(z16 + (size_t)ids.w * DFULL + c * KDIM);
  uint4 R0a = g0[0], R0b = g0[1];
  uint4 R1a = g1[0], R1b = g1[1];
  uint4 R2a = g2[0], R2b = g2[1];
  uint4 R3a = g3[0], R3b = g3[1];
  unsigned r0[8] = {R0a.x, R0a.y, R0a.z, R0a.w, R0b.x, R0b.y, R0b.z, R0b.w};
  unsigned r1[8] = {R1a.x, R1a.y, R1a.z, R1a.w, R1b.x, R1b.y, R1b.z, R1b.w};
  unsigned r2[8] = {R2a.x, R2a.y, R2a.z, R2a.w, R2b.x, R2b.y, R2b.z, R2b.w};
  unsigned r3[8] = {R3a.x, R3a.y, R3a.z, R3a.w, R3b.x, R3b.y, R3b.z, R3b.w};

  // own row, channel c slice = x residual = iter-0 u (identical across q-lanes)
  const uint4* xp = (const uint4*)(z16 + (size_t)node * DFULL + c * KDIM);
  uint4 X0 = xp[0], X1 = xp[1];
  unsigned xpk[8] = {X0.x, X0.y, X0.z, X0.w, X1.x, X1.y, X1.z, X1.w};
  unsigned upk[8];
#pragma unroll
  for (int i = 0; i < 8; ++i) upk[i] = xpk[i];

#pragma unroll
  for (int it = 0; it < ROUT_IT; ++it) {
    // ---- p-phase: agreement dots for this lane's 4 rows (TAU = 1)
    float A0 = 0.f, A1 = 0.f, A2 = 0.f, A3 = 0.f;
#pragma unroll
    for (int i = 0; i < 8; ++i) {
      A0 = fdot2(r0[i], upk[i], A0);
      A1 = fdot2(r1[i], upk[i], A1);
      A2 = fdot2(r2[i], upk[i], A2);
      A3 = fdot2(r3[i], upk[i], A3);
    }
    float e0 = __expf(A0), e1 = __expf(A1), e2 = __expf(A2), e3 = __expf(A3);
    // softmax denominator over the 8 contiguous c-lanes (same q) via DPP
    float D0 = dppadd<0x141>(dppadd<0x4E>(dppadd<0xB1>(e0)));
    float D1 = dppadd<0x141>(dppadd<0x4E>(dppadd<0xB1>(e1)));
    float D2 = dppadd<0x141>(dppadd<0x4E>(dppadd<0xB1>(e2)));
    float D3 = dppadd<0x141>(dppadd<0x4E>(dppadd<0xB1>(e3)));
    unsigned sp0, sp1, sp2, sp3;
    {
      float s0 = e0 * __builtin_amdgcn_rcpf(D0);
      float s1 = e1 * __builtin_amdgcn_rcpf(D1);
      float s2 = e2 * __builtin_amdgcn_rcpf(D2);
      float s3 = e3 * __builtin_amdgcn_rcpf(D3);
      sp0 = pk16(s0, s0); sp1 = pk16(s1, s1);
      sp2 = pk16(s2, s2); sp3 = pk16(s3, s3);
    }
    // ---- u-phase: partial weighted sum of this lane's own 4 rows (packed f16)
    unsigned acc[8];
#pragma unroll
    for (int i = 0; i < 8; ++i) {
      unsigned a = unh(h2(r3[i]) * h2(sp3));
      a = pkfma16(r2[i], sp2, a);
      a = pkfma16(r1[i], sp1, a);
      acc[i] = pkfma16(r0[i], sp0, a);
    }
    // ---- butterfly sum over the 8 q-lanes (lane bits 3,4,5)
#pragma unroll
    for (int i = 0; i < 8; ++i) {
      int v = __builtin_amdgcn_ds_swizzle((int)acc[i], 0x201F);  // lane^8
      acc[i] = unh(h2(acc[i]) + h2((unsigned)v));
    }
#pragma unroll
    for (int i = 0; i < 8; ++i) {
      int v = __builtin_amdgcn_ds_swizzle((int)acc[i], 0x401F);  // lane^16
      acc[i] = unh(h2(acc[i]) + h2((unsigned)v));
    }
#pragma unroll
    for (int i = 0; i < 8; ++i) {
      int v = __shfl_xor((int)acc[i], 32);                        // lane^32
      acc[i] = unh(h2(acc[i]) + h2((unsigned)v));
    }
    // ---- + x residual
#pragma unroll
    for (int i = 0; i < 8; ++i) acc[i] = unh(h2(acc[i]) + h2(xpk[i]));

    if (it == ROUT_IT - 1) {
      // lane writes k = 2q, 2q+1 (dword q of acc): static 8->1 select tree
      unsigned a0 = (q & 1) ? acc[1] : acc[0];
      unsigned a1 = (q & 1) ? acc[3] : acc[2];
      unsigned a2 = (q & 1) ? acc[5] : acc[4];
      unsigned a3 = (q & 1) ? acc[7] : acc[6];
      unsigned b0 = (q & 2) ? a1 : a0;
      unsigned b1 = (q & 2) ? a3 : a2;
      unsigned sel = (q & 4) ? b1 : b0;
      float2 st; st.x = h2f_lo(sel); st.y = h2f_hi(sel);
      *(float2*)(out + (size_t)node * DFULL + c * KDIM + 2 * q) = st;
    } else {
      // capsule normalize (all 16 k are local now): 8 fdot2 + rsq
      float ss = 0.f;
#pragma unroll
      for (int i = 0; i < 8; ++i) ss = fdot2(acc[i], acc[i], ss);
      float sc = __builtin_amdgcn_rsqf(fmaxf(ss, 1e-24f));
      unsigned scp = pk16(sc, sc);
#pragma unroll
      for (int i = 0; i < 8; ++i) upk[i] = unh(h2(acc[i]) * h2(scp));
    }
  }
}

// ---------------------------------------------------------------------------
extern "C" void kernel_launch(void* const* d_in, const int* in_sizes, int n_in,
                              void* d_out, int out_size, void* d_ws, size_t ws_size,
                              hipStream_t stream) {
  const float* x = (const float*)d_in[0];
  const float* W = (const float*)d_in[1];
  const float* b = (const float*)d_in[2];
  const int* nid = (const int*)d_in[3];
  float* out = (float*)d_out;

  int n = in_sizes[0] / DFULL;            // 50000
  int g1 = (n + 1 + TM1 - 1) / TM1;       // 782 (covers rows 0..n)
  size_t zrows = (size_t)g1 * TM1;        // 50048

  ushort* z16 = (ushort*)d_ws;                   // zrows x 128 f16 table
  ushort* wpk = (ushort*)d_ws + zrows * DFULL;   // 2048 x 8 f16 W fragments

  wpack_kernel<<<8, 256, 0, stream>>>(W, wpk);
  fc_mfma_kernel<<<g1, 256, 0, stream>>>(x, wpk, b, z16, n);
  routing_kernel<<<(n + 3) / 4, 256, 0, stream>>>(z16, nid, out, n);
}